// Round 1
// baseline (88.464 us; speedup 1.0000x reference)
//
#include <hip/hip_runtime.h>
#include <math.h>

#ifndef __has_builtin
#define __has_builtin(x) 0
#endif

#define GRIDC  32          // cells per axis (256 px / 8 px)
#define NCELL  1024
#define CSHIFT 3           // 8 px cells
#define RAD    4           // +-4 cells => all nodes within 32 px included.
                           // RAD must stay 4: with RAD=3 a worst-case query
                           // (nearest node ~13px, sigma^2=1) keeps r ~ e^-85
                           // while dropping r ~ e^-58 -> output corrupted.
                           // At RAD=4 dropped r <= e^-102 << any kept term.

__device__ __forceinline__ float fast_exp2(float x) {
#if __has_builtin(__builtin_amdgcn_exp2f)
    return __builtin_amdgcn_exp2f(x);
#else
    return exp2f(x);
#endif
}

__device__ __forceinline__ int cell_of(int x, int y) {
    int cx = x >> CSHIFT; cx = cx < 0 ? 0 : (cx > GRIDC - 1 ? GRIDC - 1 : cx);
    int cy = y >> CSHIFT; cy = cy < 0 ? 0 : (cy > GRIDC - 1 ? GRIDC - 1 : cy);
    return (cy << 5) + cx;
}

// ---------------------------------------------------------------------------
// Query counting sort (3 tiny dispatches + 4KB memset):
//   qhist_k:    slot[n] = atomicAdd(qcount[cell(n)], 1)
//   qscatter_k: every block redundantly scans qcount (1024 ints) in LDS,
//               then scatters its 256 queries: qidx[start[c]+slot[n]] = n.
// After this, qidx groups queries by cell (~64 queries/cell) so that the
// main kernel's lanes are spatially coherent: LDS node reads broadcast,
// trip counts align.
// ---------------------------------------------------------------------------
__global__ __launch_bounds__(256) void qhist_k(const int* __restrict__ X,
        int* __restrict__ qcount, int* __restrict__ qslot, int N) {
    int n = blockIdx.x * 256 + threadIdx.x;
    if (n >= N) return;
    int2 xy = ((const int2*)X)[n];
    qslot[n] = atomicAdd(&qcount[cell_of(xy.x, xy.y)], 1);
}

__global__ __launch_bounds__(256) void qscatter_k(const int* __restrict__ X,
        const int* __restrict__ qcount, const int* __restrict__ qslot,
        int* __restrict__ qidx, int N) {
    __shared__ int qstart[NCELL];
    __shared__ int wsum4[4];
    const int tid = threadIdx.x;
    const int lane = tid & 63;
    const int wv = tid >> 6;
    // each thread owns 4 cells; exclusive scan of 1024 counts
    int c0 = qcount[4 * tid + 0], c1 = qcount[4 * tid + 1];
    int c2 = qcount[4 * tid + 2], c3 = qcount[4 * tid + 3];
    int sum = c0 + c1 + c2 + c3;
    int incl = sum;
#pragma unroll
    for (int off = 1; off < 64; off <<= 1) {
        int t = __shfl_up(incl, off);
        if (lane >= off) incl += t;
    }
    if (lane == 63) wsum4[wv] = incl;
    __syncthreads();
    int base = 0;
#pragma unroll
    for (int w = 0; w < 4; ++w) base += (w < wv) ? wsum4[w] : 0;
    const int e = base + incl - sum;
    qstart[4 * tid + 0] = e;
    qstart[4 * tid + 1] = e + c0;
    qstart[4 * tid + 2] = e + c0 + c1;
    qstart[4 * tid + 3] = e + c0 + c1 + c2;
    __syncthreads();
    int n = blockIdx.x * 256 + tid;
    if (n < N) {
        int2 xy = ((const int2*)X)[n];
        int c = cell_of(xy.x, xy.y);
        qidx[qstart[c] + qslot[n]] = n;
    }
}

// ---------------------------------------------------------------------------
// Main kernel, sorted queries. Block: 512 threads, 128 sorted queries.
//   Phase 1: bin ALL nodes (<=2048) into LDS (unchanged, verified).
//   Phase 2: 4 lanes per query, packed INSIDE one wave: lane = {q, q+16,
//            q+32, q+48}, h = lane>>4. All 4 walk all window rows but take
//            nodes k = k0+h, k += 4 (balanced +-1). Adjacent lanes hold
//            CONSECUTIVE SORTED queries -> same cells -> identical k0/k1 ->
//            LDS reads broadcast (<=4 distinct addrs/wave), no trip-count
//            divergence. Reduction is two shfl_xor; accb buffer + one
//            barrier removed. LDS ~53.3 KB -> 2 blocks/CU, 16 waves/CU.
// ---------------------------------------------------------------------------
__global__ __launch_bounds__(512) void rbf_sorted(const int* __restrict__ X,
        const int* __restrict__ pat, const float* __restrict__ W2,
        const float* __restrict__ sig, const int* __restrict__ qidx,
        float* __restrict__ out, int N, int P) {
    __shared__ float4 sA[2048];        // {px, py, s, w0}   32 KB
    __shared__ float2 sB[2048];        // {w1, w2}          16 KB
    __shared__ int    sst[NCELL + 1];  // counts -> starts   4.1 KB
    __shared__ int    wsum[8];

    const int tid  = threadIdx.x;
    const int lane = tid & 63;
    const int wv   = tid >> 6;

    // ---- Phase 1a: zero counts ----
    for (int i = tid; i < NCELL + 1; i += 512) sst[i] = 0;
    __syncthreads();

    // ---- Phase 1b: histogram (up to 4 nodes/thread, coalesced) ----
    int cellr[4], slotr[4], xr[4], yr[4];
#pragma unroll
    for (int j = 0; j < 4; ++j) {
        int p = j * 512 + tid;
        cellr[j] = -1;
        if (p < P) {
            int2 xy = ((const int2*)pat)[p];
            xr[j] = xy.x; yr[j] = xy.y;
            int c = cell_of(xy.x, xy.y);
            cellr[j] = c;
            slotr[j] = atomicAdd(&sst[c], 1);
        }
    }
    __syncthreads();

    // ---- Phase 1c: exclusive scan of 1024 counts (thread owns 2 cells) ----
    const int c0 = sst[2 * tid], c1 = sst[2 * tid + 1];
    int sum = c0 + c1;
    int incl = sum;
#pragma unroll
    for (int off = 1; off < 64; off <<= 1) {
        int t = __shfl_up(incl, off);
        if (lane >= off) incl += t;
    }
    if (lane == 63) wsum[wv] = incl;
    __syncthreads();
    int base = 0;
#pragma unroll
    for (int w = 0; w < 8; ++w) base += (w < wv) ? wsum[w] : 0;
    const int excl0 = base + incl - sum;        // exclusive start of cell 2*tid
    __syncthreads();                            // all reads of wsum done
    sst[2 * tid + 0] = excl0;
    sst[2 * tid + 1] = excl0 + c0;
    if (tid == 511) sst[NCELL] = excl0 + c0 + c1;
    __syncthreads();

    // ---- Phase 1d: scatter node records into cell-sorted LDS ----
#pragma unroll
    for (int j = 0; j < 4; ++j) {
        if (cellr[j] >= 0) {
            int p = j * 512 + tid;
            int pos = sst[cellr[j]] + slotr[j];
            sA[pos] = make_float4((float)xr[j], (float)yr[j],
                                  -0.7213475204444817f / sig[p], W2[p]);
            sB[pos] = make_float2(W2[P + p], W2[2 * P + p]);
        }
    }
    __syncthreads();

    // ---- Phase 2: RBF over sorted queries, 4 lanes/query inside one wave ----
    const int h  = lane >> 4;                 // 0..3 node-stride phase
    const int qs = lane & 15;                 // query slot within wave
    const int j  = blockIdx.x * 128 + wv * 16 + qs;
    const bool act = j < N;

    float den = 0.f, acc0 = 0.f, acc1 = 0.f, acc2 = 0.f;
    int n0 = 0;
    if (act) {
        n0 = qidx[j];
        int2 xy = ((const int2*)X)[n0];
        const float xf = (float)xy.x, yf = (float)xy.y;
        int cx = xy.x >> CSHIFT; cx = cx < 0 ? 0 : (cx > GRIDC - 1 ? GRIDC - 1 : cx);
        int cy = xy.y >> CSHIFT; cy = cy < 0 ? 0 : (cy > GRIDC - 1 ? GRIDC - 1 : cy);
        const int x0 = cx - RAD < 0 ? 0 : cx - RAD;
        const int x1 = cx + RAD > GRIDC - 1 ? GRIDC - 1 : cx + RAD;
        const int y0 = cy - RAD < 0 ? 0 : cy - RAD;
        const int y1 = cy + RAD > GRIDC - 1 ? GRIDC - 1 : cy + RAD;
        for (int gy = y0; gy <= y1; ++gy) {
            int row = gy << 5;
            int k0 = sst[row + x0];
            int k1 = sst[row + x1 + 1];
            int k = k0 + h;
            if (k >= k1) continue;
            // software pipeline: registers hold node k; prefetch k+4 (clamped)
            float4 a = sA[k];
            float2 b = sB[k];
            for (; k < k1; k += 4) {
                int kn = k + 4 < k1 ? k + 4 : k;
                float4 an = sA[kn];
                float2 bn = sB[kn];
                float dx = xf - a.x;
                float dy = yf - a.y;
                float rr = fast_exp2(fmaf(dy, dy, dx * dx) * a.z);
                den  += rr;
                acc0 = fmaf(rr, a.w, acc0);
                acc1 = fmaf(rr, b.x, acc1);
                acc2 = fmaf(rr, b.y, acc2);
                a = an; b = bn;
            }
        }
    }

    // cross-lane reduction over the 4 phases (partners share j, so masks agree)
    den  += __shfl_xor(den,  16); acc0 += __shfl_xor(acc0, 16);
    acc1 += __shfl_xor(acc1, 16); acc2 += __shfl_xor(acc2, 16);
    den  += __shfl_xor(den,  32); acc0 += __shfl_xor(acc0, 32);
    acc1 += __shfl_xor(acc1, 32); acc2 += __shfl_xor(acc2, 32);

    if (act && h == 0) {
        float inv = 1.0f / den;
        out[3 * n0 + 0] = acc0 * inv;
        out[3 * n0 + 1] = acc1 * inv;
        out[3 * n0 + 2] = acc2 * inv;
    }
}

// ---------------------------------------------------------------------------
// Verified previous fused kernel — fallback when workspace is too small.
// ---------------------------------------------------------------------------
__global__ __launch_bounds__(512) void rbf_fused(const int* __restrict__ X,
        const int* __restrict__ pat, const float* __restrict__ W2,
        const float* __restrict__ sig, float* __restrict__ out, int N, int P) {
    __shared__ float4 sA[2048];
    __shared__ float2 sB[2048];
    __shared__ int    sst[NCELL + 1];
    __shared__ float4 accb[3 * 128];
    __shared__ int    wsum[8];

    const int tid  = threadIdx.x;
    const int lane = tid & 63;
    const int wv   = tid >> 6;

    for (int i = tid; i < NCELL + 1; i += 512) sst[i] = 0;
    __syncthreads();

    int cellr[4], slotr[4], xr[4], yr[4];
#pragma unroll
    for (int j = 0; j < 4; ++j) {
        int p = j * 512 + tid;
        cellr[j] = -1;
        if (p < P) {
            int2 xy = ((const int2*)pat)[p];
            xr[j] = xy.x; yr[j] = xy.y;
            int c = cell_of(xy.x, xy.y);
            cellr[j] = c;
            slotr[j] = atomicAdd(&sst[c], 1);
        }
    }
    __syncthreads();

    const int c0 = sst[2 * tid], c1 = sst[2 * tid + 1];
    int sum = c0 + c1;
    int incl = sum;
#pragma unroll
    for (int off = 1; off < 64; off <<= 1) {
        int t = __shfl_up(incl, off);
        if (lane >= off) incl += t;
    }
    if (lane == 63) wsum[wv] = incl;
    __syncthreads();
    int base = 0;
#pragma unroll
    for (int w = 0; w < 8; ++w) base += (w < wv) ? wsum[w] : 0;
    const int excl0 = base + incl - sum;
    __syncthreads();
    sst[2 * tid + 0] = excl0;
    sst[2 * tid + 1] = excl0 + c0;
    if (tid == 511) sst[NCELL] = excl0 + c0 + c1;
    __syncthreads();

#pragma unroll
    for (int j = 0; j < 4; ++j) {
        if (cellr[j] >= 0) {
            int p = j * 512 + tid;
            int pos = sst[cellr[j]] + slotr[j];
            sA[pos] = make_float4((float)xr[j], (float)yr[j],
                                  -0.7213475204444817f / sig[p], W2[p]);
            sB[pos] = make_float2(W2[P + p], W2[2 * P + p]);
        }
    }
    __syncthreads();

    const int quarter = tid >> 7;
    const int qi      = tid & 127;
    const int n       = blockIdx.x * 128 + qi;
    const bool act    = n < N;

    float den = 0.f, acc0 = 0.f, acc1 = 0.f, acc2 = 0.f;
    if (act) {
        int2 xy = ((const int2*)X)[n];
        const float xf = (float)xy.x, yf = (float)xy.y;
        int cx = xy.x >> CSHIFT; cx = cx < 0 ? 0 : (cx > GRIDC - 1 ? GRIDC - 1 : cx);
        int cy = xy.y >> CSHIFT; cy = cy < 0 ? 0 : (cy > GRIDC - 1 ? GRIDC - 1 : cy);
        const int x0 = cx - RAD < 0 ? 0 : cx - RAD;
        const int x1 = cx + RAD > GRIDC - 1 ? GRIDC - 1 : cx + RAD;
        const int r0 = (9 * quarter) >> 2;
        const int r1 = (9 * (quarter + 1)) >> 2;
        for (int r = r0; r < r1; ++r) {
            int gy = cy - RAD + r;
            if ((unsigned)gy >= GRIDC) continue;
            int row = gy << 5;
            int k0 = sst[row + x0];
            int k1 = sst[row + x1 + 1];
            if (k0 >= k1) continue;
            float4 a = sA[k0];
            float2 b = sB[k0];
            for (int k = k0; k < k1; ++k) {
                int kn = k + 1 < k1 ? k + 1 : k;
                float4 an = sA[kn];
                float2 bn = sB[kn];
                float dx = xf - a.x;
                float dy = yf - a.y;
                float rr = fast_exp2(fmaf(dy, dy, dx * dx) * a.z);
                den  += rr;
                acc0 = fmaf(rr, a.w, acc0);
                acc1 = fmaf(rr, b.x, acc1);
                acc2 = fmaf(rr, b.y, acc2);
                a = an; b = bn;
            }
        }
    }

    if (quarter) accb[(quarter - 1) * 128 + qi] = make_float4(den, acc0, acc1, acc2);
    __syncthreads();
    if (quarter == 0 && act) {
#pragma unroll
        for (int w = 0; w < 3; ++w) {
            float4 u = accb[w * 128 + qi];
            den += u.x; acc0 += u.y; acc1 += u.z; acc2 += u.w;
        }
        float inv = 1.0f / den;
        out[3 * n + 0] = acc0 * inv;
        out[3 * n + 1] = acc1 * inv;
        out[3 * n + 2] = acc2 * inv;
    }
}

// ---------------------------------------------------------------------------
// Generic fallback (unexpected sizes): brute-force N x P sweep.
// ---------------------------------------------------------------------------
__global__ void pack_nodes(const int* __restrict__ pat, const float* __restrict__ W2,
                           const float* __restrict__ sigmaSq, float* __restrict__ nodes,
                           int P) {
    int p = blockIdx.x * blockDim.x + threadIdx.x;
    if (p >= P) return;
    float* q = nodes + 8 * (size_t)p;
    q[0] = (float)pat[2 * p];
    q[1] = (float)pat[2 * p + 1];
    q[2] = -0.7213475204444817f / sigmaSq[p];
    q[3] = W2[p];
    q[4] = W2[P + p];
    q[5] = W2[2 * P + p];
    q[6] = 0.0f;
    q[7] = 0.0f;
}

__global__ __launch_bounds__(256) void rbf_main_dyn(const int* __restrict__ X,
                                                    const float* __restrict__ nodes,
                                                    float* __restrict__ outp,
                                                    int N, int P) {
    int n = blockIdx.x * 256 + threadIdx.x;
    if (n >= N) return;
    float xn = (float)X[2 * n], yn = (float)X[2 * n + 1];
    float den = 0.f, a0 = 0.f, a1 = 0.f, a2 = 0.f;
    for (int j = 0; j < P; ++j) {
        const float* q = nodes + (size_t)j * 8;
        float dx = xn - q[0], dy = yn - q[1];
        float r = fast_exp2(fmaf(dy, dy, dx * dx) * q[2]);
        den += r;
        a0 = fmaf(r, q[3], a0);
        a1 = fmaf(r, q[4], a1);
        a2 = fmaf(r, q[5], a2);
    }
    outp[3 * n + 0] = a0 / den;
    outp[3 * n + 1] = a1 / den;
    outp[3 * n + 2] = a2 / den;
}

extern "C" void kernel_launch(void* const* d_in, const int* in_sizes, int n_in,
                              void* d_out, int out_size, void* d_ws, size_t ws_size,
                              hipStream_t stream) {
    const int*   X   = (const int*)d_in[0];
    const int*   pat = (const int*)d_in[1];
    const float* W2  = (const float*)d_in[2];
    const float* sig = (const float*)d_in[3];
    float*       out = (float*)d_out;

    const int N = in_sizes[0] / 2;
    const int P = in_sizes[3];

    if (P <= 2048 && out_size == 3 * N) {
        const size_t need = (size_t)(NCELL + 2 * (size_t)N) * sizeof(int);
        if (ws_size >= need && N >= 4096) {
            int* qcount = (int*)d_ws;
            int* qslot  = qcount + NCELL;
            int* qidx   = qslot + N;
            hipMemsetAsync(qcount, 0, NCELL * sizeof(int), stream);
            qhist_k<<<dim3((N + 255) / 256), dim3(256), 0, stream>>>(X, qcount, qslot, N);
            qscatter_k<<<dim3((N + 255) / 256), dim3(256), 0, stream>>>(X, qcount, qslot, qidx, N);
            rbf_sorted<<<dim3((N + 127) / 128), dim3(512), 0, stream>>>(
                X, pat, W2, sig, qidx, out, N, P);
        } else {
            rbf_fused<<<dim3((N + 127) / 128), dim3(512), 0, stream>>>(
                X, pat, W2, sig, out, N, P);
        }
    } else {
        float* nodes = (float*)d_ws;
        pack_nodes<<<dim3((P + 255) / 256), dim3(256), 0, stream>>>(pat, W2, sig, nodes, P);
        rbf_main_dyn<<<dim3((N + 255) / 256), dim3(256), 0, stream>>>(X, nodes, out, N, P);
    }
}

// Round 2
// 70.773 us; speedup vs baseline: 1.2500x; 1.2500x over previous
//
#include <hip/hip_runtime.h>
#include <math.h>

#ifndef __has_builtin
#define __has_builtin(x) 0
#endif

#define GRIDC  32          // cells per axis (256 px / 8 px)
#define NCELL  1024
#define CSHIFT 3           // 8 px cells
#define RAD    4           // +-4 cells => all nodes within 32 px included.
                           // RAD must stay 4: with RAD=3 a worst-case query
                           // (nearest node ~13px, sigma^2=1) keeps r ~ e^-85
                           // while dropping r ~ e^-58 -> output corrupted.
                           // At RAD=4 dropped r <= e^-102 << any kept term.

__device__ __forceinline__ float fast_exp2(float x) {
#if __has_builtin(__builtin_amdgcn_exp2f)
    return __builtin_amdgcn_exp2f(x);
#else
    return exp2f(x);
#endif
}

__device__ __forceinline__ int cell_of(int x, int y) {
    int cx = x >> CSHIFT; cx = cx < 0 ? 0 : (cx > GRIDC - 1 ? GRIDC - 1 : cx);
    int cy = y >> CSHIFT; cy = cy < 0 ? 0 : (cy > GRIDC - 1 ? GRIDC - 1 : cy);
    return (cy << 5) + cx;
}

// ---------------------------------------------------------------------------
// Single fused kernel (ONE dispatch — round 1 showed each extra dispatch
// costs ~5 us, more than any sort-derived win).
// Block: 512 threads, 128 queries, 8 LANES PER QUERY (two sequential passes
// of 64 groups). Lane l8 of a group takes nodes k0+l8, +8, ... so the 8
// lanes read 8 CONSECUTIVE sA/sB records: 128B contiguous LDS runs sweep
// all 32 banks evenly -> ~zero bank conflicts (vs 64 random 16B gathers in
// the round-0 4-thread/query layout). Inner-trip divergence shrinks from
// max-over-64-lanes to max-over-8-groups. Reduction: 3 shfl_xor stages
// (DPP-cheap); no accb LDS buffer, no final barrier.
// LDS ~52.3 KB -> 2 blocks/CU, 16 waves/CU.
// ---------------------------------------------------------------------------
__global__ __launch_bounds__(512) void rbf_g8(const int* __restrict__ X,
        const int* __restrict__ pat, const float* __restrict__ W2,
        const float* __restrict__ sig, float* __restrict__ out, int N, int P) {
    __shared__ float4 sA[2048];        // {px, py, s, w0}   32 KB
    __shared__ float2 sB[2048];        // {w1, w2}          16 KB
    __shared__ int    sst[NCELL + 1];  // counts -> starts   4.1 KB
    __shared__ int    wsum[8];

    const int tid  = threadIdx.x;
    const int lane = tid & 63;
    const int wv   = tid >> 6;

    // ---- Phase 1a: zero counts ----
    for (int i = tid; i < NCELL + 1; i += 512) sst[i] = 0;
    __syncthreads();

    // ---- Phase 1b: histogram (up to 4 nodes/thread, coalesced) ----
    int cellr[4], slotr[4], xr[4], yr[4];
#pragma unroll
    for (int j = 0; j < 4; ++j) {
        int p = j * 512 + tid;
        cellr[j] = -1;
        if (p < P) {
            int2 xy = ((const int2*)pat)[p];
            xr[j] = xy.x; yr[j] = xy.y;
            int c = cell_of(xy.x, xy.y);
            cellr[j] = c;
            slotr[j] = atomicAdd(&sst[c], 1);
        }
    }
    __syncthreads();

    // ---- Phase 1c: exclusive scan of 1024 counts (thread owns 2 cells) ----
    const int c0 = sst[2 * tid], c1 = sst[2 * tid + 1];
    int sum = c0 + c1;
    int incl = sum;
#pragma unroll
    for (int off = 1; off < 64; off <<= 1) {
        int t = __shfl_up(incl, off);
        if (lane >= off) incl += t;
    }
    if (lane == 63) wsum[wv] = incl;
    __syncthreads();
    int base = 0;
#pragma unroll
    for (int w = 0; w < 8; ++w) base += (w < wv) ? wsum[w] : 0;
    const int excl0 = base + incl - sum;        // exclusive start of cell 2*tid
    __syncthreads();                            // all reads of wsum done
    sst[2 * tid + 0] = excl0;
    sst[2 * tid + 1] = excl0 + c0;
    if (tid == 511) sst[NCELL] = excl0 + c0 + c1;
    __syncthreads();

    // ---- Phase 1d: scatter node records into cell-sorted LDS ----
#pragma unroll
    for (int j = 0; j < 4; ++j) {
        if (cellr[j] >= 0) {
            int p = j * 512 + tid;
            int pos = sst[cellr[j]] + slotr[j];
            sA[pos] = make_float4((float)xr[j], (float)yr[j],
                                  -0.7213475204444817f / sig[p], W2[p]);
            sB[pos] = make_float2(W2[P + p], W2[2 * P + p]);
        }
    }
    __syncthreads();

    // ---- Phase 2: 8 lanes per query, 2 sequential queries per group ----
    const int g   = tid >> 3;          // group 0..63
    const int l8  = tid & 7;           // lane within group
    const int nb  = blockIdx.x * 128;

#pragma unroll
    for (int pass = 0; pass < 2; ++pass) {
        const int n  = nb + pass * 64 + g;
        const bool act = n < N;

        float den = 0.f, acc0 = 0.f, acc1 = 0.f, acc2 = 0.f;
        if (act) {
            int2 xy = ((const int2*)X)[n];     // 8-lane broadcast read
            const float xf = (float)xy.x, yf = (float)xy.y;
            int cx = xy.x >> CSHIFT; cx = cx < 0 ? 0 : (cx > GRIDC - 1 ? GRIDC - 1 : cx);
            int cy = xy.y >> CSHIFT; cy = cy < 0 ? 0 : (cy > GRIDC - 1 ? GRIDC - 1 : cy);
            const int x0 = cx - RAD < 0 ? 0 : cx - RAD;
            const int x1 = cx + RAD > GRIDC - 1 ? GRIDC - 1 : cx + RAD;
#pragma unroll
            for (int r = 0; r < 2 * RAD + 1; ++r) {
                int gy = cy - RAD + r;
                if ((unsigned)gy >= GRIDC) continue;
                int row = gy << 5;
                int k0 = sst[row + x0];        // broadcast within group
                int k1 = sst[row + x1 + 1];
                int k = k0 + l8;
                if (k >= k1) continue;
                // software pipeline: regs hold node k; prefetch k+8 (clamped)
                float4 a = sA[k];
                float2 b = sB[k];
                for (; k < k1; k += 8) {
                    int kn = k + 8 < k1 ? k + 8 : k;
                    float4 an = sA[kn];
                    float2 bn = sB[kn];
                    float dx = xf - a.x;
                    float dy = yf - a.y;
                    float rr = fast_exp2(fmaf(dy, dy, dx * dx) * a.z);
                    den  += rr;
                    acc0 = fmaf(rr, a.w, acc0);
                    acc1 = fmaf(rr, b.x, acc1);
                    acc2 = fmaf(rr, b.y, acc2);
                    a = an; b = bn;
                }
            }
        }

        // 8-lane reduction (strides 1/2/4 -> DPP-cheap; partners share n)
        den  += __shfl_xor(den,  1); acc0 += __shfl_xor(acc0, 1);
        acc1 += __shfl_xor(acc1, 1); acc2 += __shfl_xor(acc2, 1);
        den  += __shfl_xor(den,  2); acc0 += __shfl_xor(acc0, 2);
        acc1 += __shfl_xor(acc1, 2); acc2 += __shfl_xor(acc2, 2);
        den  += __shfl_xor(den,  4); acc0 += __shfl_xor(acc0, 4);
        acc1 += __shfl_xor(acc1, 4); acc2 += __shfl_xor(acc2, 4);

        if (act && l8 == 0) {
            float inv = 1.0f / den;
            out[3 * n + 0] = acc0 * inv;
            out[3 * n + 1] = acc1 * inv;
            out[3 * n + 2] = acc2 * inv;
        }
    }
}

// ---------------------------------------------------------------------------
// Generic fallback (unexpected sizes): brute-force N x P sweep.
// ---------------------------------------------------------------------------
__global__ void pack_nodes(const int* __restrict__ pat, const float* __restrict__ W2,
                           const float* __restrict__ sigmaSq, float* __restrict__ nodes,
                           int P) {
    int p = blockIdx.x * blockDim.x + threadIdx.x;
    if (p >= P) return;
    float* q = nodes + 8 * (size_t)p;
    q[0] = (float)pat[2 * p];
    q[1] = (float)pat[2 * p + 1];
    q[2] = -0.7213475204444817f / sigmaSq[p];
    q[3] = W2[p];
    q[4] = W2[P + p];
    q[5] = W2[2 * P + p];
    q[6] = 0.0f;
    q[7] = 0.0f;
}

__global__ __launch_bounds__(256) void rbf_main_dyn(const int* __restrict__ X,
                                                    const float* __restrict__ nodes,
                                                    float* __restrict__ outp,
                                                    int N, int P) {
    int n = blockIdx.x * 256 + threadIdx.x;
    if (n >= N) return;
    float xn = (float)X[2 * n], yn = (float)X[2 * n + 1];
    float den = 0.f, a0 = 0.f, a1 = 0.f, a2 = 0.f;
    for (int j = 0; j < P; ++j) {
        const float* q = nodes + (size_t)j * 8;
        float dx = xn - q[0], dy = yn - q[1];
        float r = fast_exp2(fmaf(dy, dy, dx * dx) * q[2]);
        den += r;
        a0 = fmaf(r, q[3], a0);
        a1 = fmaf(r, q[4], a1);
        a2 = fmaf(r, q[5], a2);
    }
    outp[3 * n + 0] = a0 / den;
    outp[3 * n + 1] = a1 / den;
    outp[3 * n + 2] = a2 / den;
}

extern "C" void kernel_launch(void* const* d_in, const int* in_sizes, int n_in,
                              void* d_out, int out_size, void* d_ws, size_t ws_size,
                              hipStream_t stream) {
    const int*   X   = (const int*)d_in[0];
    const int*   pat = (const int*)d_in[1];
    const float* W2  = (const float*)d_in[2];
    const float* sig = (const float*)d_in[3];
    float*       out = (float*)d_out;

    const int N = in_sizes[0] / 2;
    const int P = in_sizes[3];

    if (P <= 2048 && out_size == 3 * N) {
        rbf_g8<<<dim3((N + 127) / 128), dim3(512), 0, stream>>>(
            X, pat, W2, sig, out, N, P);
    } else {
        float* nodes = (float*)d_ws;
        pack_nodes<<<dim3((P + 255) / 256), dim3(256), 0, stream>>>(pat, W2, sig, nodes, P);
        rbf_main_dyn<<<dim3((N + 255) / 256), dim3(256), 0, stream>>>(X, nodes, out, N, P);
    }
}

// Round 3
// 69.371 us; speedup vs baseline: 1.2752x; 1.0202x over previous
//
#include <hip/hip_runtime.h>
#include <math.h>

#ifndef __has_builtin
#define __has_builtin(x) 0
#endif

#define GRIDC  32          // cells per axis (256 px / 8 px)
#define NCELL  1024
#define CSHIFT 3           // 8 px cells
#define RAD    4           // +-4 cells => all nodes within 32 px included.
                           // RAD must stay 4: with RAD=3 a worst-case query
                           // (nearest node ~13px, sigma^2=1) keeps r ~ e^-85
                           // while dropping r ~ e^-58 -> output corrupted.
                           // At RAD=4 dropped r <= e^-102 << any kept term.
#define NPAD   2056        // 2048 nodes + 8 pad entries so the software
                           // pipeline can prefetch sA[k+4] unconditionally
                           // (junk is rotated out, never computed on).

__device__ __forceinline__ float fast_exp2(float x) {
#if __has_builtin(__builtin_amdgcn_exp2f)
    return __builtin_amdgcn_exp2f(x);
#else
    return exp2f(x);
#endif
}

__device__ __forceinline__ int cell_of(int x, int y) {
    int cx = x >> CSHIFT; cx = cx < 0 ? 0 : (cx > GRIDC - 1 ? GRIDC - 1 : cx);
    int cy = y >> CSHIFT; cy = cy < 0 ? 0 : (cy > GRIDC - 1 ? GRIDC - 1 : cy);
    return (cy << 5) + cx;
}

// ---------------------------------------------------------------------------
// Single fused kernel, ONE dispatch (round 1: each extra dispatch ~4-5 us).
// Block: 512 threads, 128 queries, 4 CONSECUTIVE LANES per query, one pass.
//   - 4-lane groups: slot waste ceil(nk/4)*4 ~ 11% (vs 33% for 8-lane),
//     64B contiguous LDS runs, 2-stage DPP shfl_xor reduction.
//   - Row loop NOT unrolled + no prefetch clamp (padded LDS) to keep
//     VGPR <= 128: __launch_bounds__(512,4) guarantees 2 blocks/CU
//     (16 waves/CU) so the ~120cyc LDS dependent chain is hidden.
//     Round-2 suspicion: the 9x-unrolled pipelined loop spilled past 128
//     VGPR -> 1 block/CU -> latency-bound. This version pins occupancy.
//   - Final store: lane l4<3 writes out[3n+l4]; consecutive groups hold
//     consecutive n -> one contiguous 48-dword store per wave.
// LDS ~52.2 KB.
// ---------------------------------------------------------------------------
__global__ __launch_bounds__(512, 4) void rbf_g4(const int* __restrict__ X,
        const int* __restrict__ pat, const float* __restrict__ W2,
        const float* __restrict__ sig, float* __restrict__ out, int N, int P) {
    __shared__ float4 sA[NPAD];        // {px, py, s, w0}   32.9 KB
    __shared__ float2 sB[NPAD];        // {w1, w2}          16.4 KB
    __shared__ int    sst[NCELL + 1];  // counts -> starts   4.1 KB
    __shared__ int    wsum[8];

    const int tid  = threadIdx.x;
    const int lane = tid & 63;
    const int wv   = tid >> 6;

    // ---- Phase 1a: zero counts ----
    for (int i = tid; i < NCELL + 1; i += 512) sst[i] = 0;
    __syncthreads();

    // ---- Phase 1b: histogram (up to 4 nodes/thread, coalesced) ----
    int cellr[4], slotr[4], xr[4], yr[4];
#pragma unroll
    for (int j = 0; j < 4; ++j) {
        int p = j * 512 + tid;
        cellr[j] = -1;
        if (p < P) {
            int2 xy = ((const int2*)pat)[p];
            xr[j] = xy.x; yr[j] = xy.y;
            int c = cell_of(xy.x, xy.y);
            cellr[j] = c;
            slotr[j] = atomicAdd(&sst[c], 1);
        }
    }
    __syncthreads();

    // ---- Phase 1c: exclusive scan of 1024 counts (thread owns 2 cells) ----
    const int c0 = sst[2 * tid], c1 = sst[2 * tid + 1];
    int sum = c0 + c1;
    int incl = sum;
#pragma unroll
    for (int off = 1; off < 64; off <<= 1) {
        int t = __shfl_up(incl, off);
        if (lane >= off) incl += t;
    }
    if (lane == 63) wsum[wv] = incl;
    __syncthreads();
    int base = 0;
#pragma unroll
    for (int w = 0; w < 8; ++w) base += (w < wv) ? wsum[w] : 0;
    const int excl0 = base + incl - sum;        // exclusive start of cell 2*tid
    __syncthreads();                            // all reads of wsum done
    sst[2 * tid + 0] = excl0;
    sst[2 * tid + 1] = excl0 + c0;
    if (tid == 511) sst[NCELL] = excl0 + c0 + c1;
    __syncthreads();

    // ---- Phase 1d: scatter node records into cell-sorted LDS ----
#pragma unroll
    for (int j = 0; j < 4; ++j) {
        if (cellr[j] >= 0) {
            int p = j * 512 + tid;
            int pos = sst[cellr[j]] + slotr[j];
            sA[pos] = make_float4((float)xr[j], (float)yr[j],
                                  -0.7213475204444817f / sig[p], W2[p]);
            sB[pos] = make_float2(W2[P + p], W2[2 * P + p]);
        }
    }
    __syncthreads();

    // ---- Phase 2: 4 consecutive lanes per query, one pass ----
    const int g   = tid >> 2;          // group 0..127  (16 groups per wave)
    const int l4  = tid & 3;           // lane within group
    const int n   = blockIdx.x * 128 + g;
    const bool act = n < N;

    float den = 0.f, acc0 = 0.f, acc1 = 0.f, acc2 = 0.f;
    if (act) {
        int2 xy = ((const int2*)X)[n];     // 4-lane broadcast read
        const float xf = (float)xy.x, yf = (float)xy.y;
        int cx = xy.x >> CSHIFT; cx = cx < 0 ? 0 : (cx > GRIDC - 1 ? GRIDC - 1 : cx);
        int cy = xy.y >> CSHIFT; cy = cy < 0 ? 0 : (cy > GRIDC - 1 ? GRIDC - 1 : cy);
        const int x0 = cx - RAD < 0 ? 0 : cx - RAD;
        const int x1 = cx + RAD > GRIDC - 1 ? GRIDC - 1 : cx + RAD;
        const int y0 = cy - RAD < 0 ? 0 : cy - RAD;
        const int y1 = cy + RAD > GRIDC - 1 ? GRIDC - 1 : cy + RAD;
        for (int gy = y0; gy <= y1; ++gy) {    // dynamic: keeps VGPR low
            int row = gy << 5;
            int k0 = sst[row + x0];            // broadcast within group
            int k1 = sst[row + x1 + 1];
            int k = k0 + l4;
            if (k >= k1) continue;
            // software pipeline, NO clamp: prefetch k+4 from padded LDS
            float4 a = sA[k];
            float2 b = sB[k];
            for (; k < k1; k += 4) {
                float4 an = sA[k + 4];
                float2 bn = sB[k + 4];
                float dx = xf - a.x;
                float dy = yf - a.y;
                float rr = fast_exp2(fmaf(dy, dy, dx * dx) * a.z);
                den  += rr;
                acc0 = fmaf(rr, a.w, acc0);
                acc1 = fmaf(rr, b.x, acc1);
                acc2 = fmaf(rr, b.y, acc2);
                a = an; b = bn;
            }
        }
    }

    // 4-lane reduction (strides 1/2 -> DPP-cheap; partners share n)
    den  += __shfl_xor(den,  1); acc0 += __shfl_xor(acc0, 1);
    acc1 += __shfl_xor(acc1, 1); acc2 += __shfl_xor(acc2, 1);
    den  += __shfl_xor(den,  2); acc0 += __shfl_xor(acc0, 2);
    acc1 += __shfl_xor(acc1, 2); acc2 += __shfl_xor(acc2, 2);

    // contiguous wave store: lane l4 in {0,1,2} writes out[3n+l4]
    if (act && l4 < 3) {
        float inv = 1.0f / den;
        float v = (l4 == 0) ? acc0 : ((l4 == 1) ? acc1 : acc2);
        out[3 * n + l4] = v * inv;
    }
}

// ---------------------------------------------------------------------------
// Generic fallback (unexpected sizes): brute-force N x P sweep.
// ---------------------------------------------------------------------------
__global__ void pack_nodes(const int* __restrict__ pat, const float* __restrict__ W2,
                           const float* __restrict__ sigmaSq, float* __restrict__ nodes,
                           int P) {
    int p = blockIdx.x * blockDim.x + threadIdx.x;
    if (p >= P) return;
    float* q = nodes + 8 * (size_t)p;
    q[0] = (float)pat[2 * p];
    q[1] = (float)pat[2 * p + 1];
    q[2] = -0.7213475204444817f / sigmaSq[p];
    q[3] = W2[p];
    q[4] = W2[P + p];
    q[5] = W2[2 * P + p];
    q[6] = 0.0f;
    q[7] = 0.0f;
}

__global__ __launch_bounds__(256) void rbf_main_dyn(const int* __restrict__ X,
                                                    const float* __restrict__ nodes,
                                                    float* __restrict__ outp,
                                                    int N, int P) {
    int n = blockIdx.x * 256 + threadIdx.x;
    if (n >= N) return;
    float xn = (float)X[2 * n], yn = (float)X[2 * n + 1];
    float den = 0.f, a0 = 0.f, a1 = 0.f, a2 = 0.f;
    for (int j = 0; j < P; ++j) {
        const float* q = nodes + (size_t)j * 8;
        float dx = xn - q[0], dy = yn - q[1];
        float r = fast_exp2(fmaf(dy, dy, dx * dx) * q[2]);
        den += r;
        a0 = fmaf(r, q[3], a0);
        a1 = fmaf(r, q[4], a1);
        a2 = fmaf(r, q[5], a2);
    }
    outp[3 * n + 0] = a0 / den;
    outp[3 * n + 1] = a1 / den;
    outp[3 * n + 2] = a2 / den;
}

extern "C" void kernel_launch(void* const* d_in, const int* in_sizes, int n_in,
                              void* d_out, int out_size, void* d_ws, size_t ws_size,
                              hipStream_t stream) {
    const int*   X   = (const int*)d_in[0];
    const int*   pat = (const int*)d_in[1];
    const float* W2  = (const float*)d_in[2];
    const float* sig = (const float*)d_in[3];
    float*       out = (float*)d_out;

    const int N = in_sizes[0] / 2;
    const int P = in_sizes[3];

    if (P <= 2048 && out_size == 3 * N) {
        rbf_g4<<<dim3((N + 127) / 128), dim3(512), 0, stream>>>(
            X, pat, W2, sig, out, N, P);
    } else {
        float* nodes = (float*)d_ws;
        pack_nodes<<<dim3((P + 255) / 256), dim3(256), 0, stream>>>(pat, W2, sig, nodes, P);
        rbf_main_dyn<<<dim3((N + 255) / 256), dim3(256), 0, stream>>>(X, nodes, out, N, P);
    }
}